// Round 1
// baseline (174.762 us; speedup 1.0000x reference)
//
#include <hip/hip_runtime.h>
#include <hip/hip_bf16.h>

// MoE MLP: x[1,2048,768] fp32, router_w[16,768], w1[768,12288], w2[12288,768]
// out[1,2048,768] fp32.  Experts: 8x512 + 8x1024, top-8, normalized.
// Strategy: dense bf16 GEMMs (reference is dense+masked); comb folded into H.

#define T_TOK 2048
#define D_EMB 768
#define W_TOT 12288
#define N_EXP 16

typedef __attribute__((ext_vector_type(4))) float f32x4;
typedef __attribute__((ext_vector_type(8))) short bf16x8;

typedef __attribute__((address_space(1))) const unsigned int as1c_u32;
typedef __attribute__((address_space(3))) unsigned int as3_u32;

__device__ __forceinline__ void gload16(const void* g, void* l) {
  __builtin_amdgcn_global_load_lds((as1c_u32*)g, (as3_u32*)l, 16, 0, 0);
}

__device__ __forceinline__ unsigned short f2bf(float f) {
  __hip_bfloat16 h = __float2bfloat16(f);
  return *reinterpret_cast<unsigned short*>(&h);
}

__device__ __forceinline__ float gelu_f(float x) {
  // jax.nn.gelu default (approximate=True, tanh form)
  float x3 = x * x * x;
  float a = 0.7978845608028654f * __builtin_fmaf(0.044715f, x3, x);
  a = fminf(fmaxf(a, -20.f), 20.f);
  float e = __expf(-2.0f * a);
  float t = (1.0f - e) / (1.0f + e);
  return 0.5f * x * (1.0f + t);
}

// ---------------- conversion kernels ----------------

__global__ __launch_bounds__(256) void cvt_bf16_kernel(
    const float* __restrict__ in, unsigned short* __restrict__ out, int n) {
  int i = (blockIdx.x * 256 + threadIdx.x) * 4;
  if (i >= n) return;
  float4 v = *(const float4*)(in + i);
  ushort4 o;
  o.x = f2bf(v.x); o.y = f2bf(v.y); o.z = f2bf(v.z); o.w = f2bf(v.w);
  *(ushort4*)(out + i) = o;
}

// in fp32 [R][C] -> out bf16 [C][R]
__global__ __launch_bounds__(256) void transpose_cvt_kernel(
    const float* __restrict__ in, unsigned short* __restrict__ out, int R, int C) {
  __shared__ float tile[32][33];
  int c0 = blockIdx.x * 32;  // along C
  int r0 = blockIdx.y * 32;  // along R
  int i = threadIdx.x;
  {
    int r = i >> 3, c4 = (i & 7) * 4;
    float4 v = *(const float4*)(in + (size_t)(r0 + r) * C + c0 + c4);
    tile[r][c4 + 0] = v.x; tile[r][c4 + 1] = v.y;
    tile[r][c4 + 2] = v.z; tile[r][c4 + 3] = v.w;
  }
  __syncthreads();
  {
    int c = i >> 3, r4 = (i & 7) * 4;
    ushort4 o;
    o.x = f2bf(tile[r4 + 0][c]);
    o.y = f2bf(tile[r4 + 1][c]);
    o.z = f2bf(tile[r4 + 2][c]);
    o.w = f2bf(tile[r4 + 3][c]);
    *(ushort4*)(out + (size_t)(c0 + c) * R + r0 + r4) = o;
  }
}

// ---------------- router ----------------
// one wave per token; every lane redundantly holds all 16 logits after
// butterfly reduce; rank-based top-8 with index tie-break (static indices only)

__global__ __launch_bounds__(256) void router_kernel(
    const float* __restrict__ x, const float* __restrict__ rw,
    float* __restrict__ comb) {
  int tid = threadIdx.x, lane = tid & 63, w = tid >> 6;
  int t = blockIdx.x * 4 + w;
  const float* xr = x + (size_t)t * D_EMB;
  float xv[12];
#pragma unroll
  for (int i = 0; i < 12; ++i) xv[i] = xr[lane + 64 * i];
  float lg[16];
#pragma unroll
  for (int e = 0; e < 16; ++e) {
    const float* we = rw + (size_t)e * D_EMB;
    float p = 0.f;
#pragma unroll
    for (int i = 0; i < 12; ++i) p = __builtin_fmaf(xv[i], we[lane + 64 * i], p);
#pragma unroll
    for (int off = 32; off >= 1; off >>= 1) p += __shfl_xor(p, off, 64);
    lg[e] = p;
  }
  float mx = lg[0];
#pragma unroll
  for (int e = 1; e < 16; ++e) mx = fmaxf(mx, lg[e]);
  float ex[16];
#pragma unroll
  for (int e = 0; e < 16; ++e) ex[e] = __expf(lg[e] - mx);
  // rank each expert; top-8 selected; softmax denom cancels under renorm
  float selsum = 0.f, myval = 0.f;
#pragma unroll
  for (int e = 0; e < 16; ++e) {
    int rank = 0;
#pragma unroll
    for (int e2 = 0; e2 < 16; ++e2)
      rank += (ex[e2] > ex[e]) || (ex[e2] == ex[e] && e2 < e);
    bool sel = rank < 8;
    float v = sel ? ex[e] : 0.f;
    selsum += v;
    if (e == lane) myval = v;
  }
  if (lane < 16) comb[(size_t)t * N_EXP + lane] = myval / selsum;
}

// ---------------- GEMM1: H = gelu(X @ W1) * comb ----------------
// X bf16 [2048][768], W1T bf16 [12288][768] (N-major), H bf16 [2048][12288]
// 128x128 tile, BK=64, 4 waves (2x2), 16x16x32 MFMA, m97-style 2-barrier loop.

__global__ __launch_bounds__(256, 2) void gemm1_kernel(
    const unsigned short* __restrict__ xb, const unsigned short* __restrict__ w1t,
    const float* __restrict__ comb, unsigned short* __restrict__ h) {
  __shared__ __align__(16) unsigned short As[128 * 64];
  __shared__ __align__(16) unsigned short Bs[128 * 64];
  __shared__ __align__(16) float Cw[128 * 16];

  const int tid = threadIdx.x;
  const int lane = tid & 63;
  const int wid = tid >> 6;
  const int wr = wid >> 1, wc = wid & 1;
  const int rm0 = blockIdx.y * 128;
  const int cn0 = blockIdx.x * 128;

  {  // stage comb rows for this M-block: [128][16] fp32
    int r = tid >> 1, c8 = (tid & 1) * 8;
    const float4* s = (const float4*)(comb + (size_t)(rm0 + r) * N_EXP + c8);
    float4 v0 = s[0], v1 = s[1];
    *(float4*)&Cw[r * 16 + c8] = v0;
    *(float4*)&Cw[r * 16 + c8 + 4] = v1;
  }

  f32x4 acc[4][4];
#pragma unroll
  for (int m = 0; m < 4; ++m)
#pragma unroll
    for (int n = 0; n < 4; ++n) acc[m][n] = (f32x4){0.f, 0.f, 0.f, 0.f};

  const char* abase = (const char*)xb;
  const char* bbase = (const char*)w1t;

  for (int k0 = 0; k0 < D_EMB; k0 += 64) {
    __syncthreads();
#pragma unroll
    for (int j = 0; j < 4; ++j) {
      int f = j * 4096 + tid * 16;
      int row = f >> 7, inrow = f & 127;
      gload16(abase + ((size_t)(rm0 + row) * D_EMB + k0) * 2 + inrow,
              (char*)As + j * 4096 + wid * 1024);
      gload16(bbase + ((size_t)(cn0 + row) * D_EMB + k0) * 2 + inrow,
              (char*)Bs + j * 4096 + wid * 1024);
    }
    __syncthreads();
#pragma unroll
    for (int kk = 0; kk < 2; ++kk) {
      bf16x8 af[4], bfr[4];
#pragma unroll
      for (int m = 0; m < 4; ++m)
        af[m] = *(const bf16x8*)((const char*)As +
                 (wr * 64 + m * 16 + (lane & 15)) * 128 + kk * 64 + (lane >> 4) * 16);
#pragma unroll
      for (int n = 0; n < 4; ++n)
        bfr[n] = *(const bf16x8*)((const char*)Bs +
                 (wc * 64 + n * 16 + (lane & 15)) * 128 + kk * 64 + (lane >> 4) * 16);
#pragma unroll
      for (int m = 0; m < 4; ++m)
#pragma unroll
        for (int n = 0; n < 4; ++n)
          acc[m][n] = __builtin_amdgcn_mfma_f32_16x16x32_bf16(af[m], bfr[n], acc[m][n], 0, 0, 0);
    }
  }

  const int r0 = (lane >> 4) * 4;
  const int cl = lane & 15;
#pragma unroll
  for (int n = 0; n < 4; ++n) {
    int ecol = cn0 + wc * 64 + n * 16;  // expert uniform per 16-col frag
    int e = (ecol < 4096) ? (ecol >> 9) : (8 + ((ecol - 4096) >> 10));
    int ng = ecol + cl;
#pragma unroll
    for (int m = 0; m < 4; ++m) {
      int rl = wr * 64 + m * 16 + r0;
#pragma unroll
      for (int r = 0; r < 4; ++r) {
        float z = acc[m][n][r];
        float wgt = Cw[(rl + r) * 16 + e];
        float v = gelu_f(z) * wgt;
        h[(size_t)(rm0 + rl + r) * W_TOT + ng] = f2bf(v);
      }
    }
  }
}

// ---------------- GEMM2: OUT = H @ W2 (split-K) ----------------
// H bf16 [2048][12288], W2T bf16 [768][12288] (N-major), partial fp32 per split

__global__ __launch_bounds__(256, 2) void gemm2_kernel(
    const unsigned short* __restrict__ hA, const unsigned short* __restrict__ w2t,
    float* __restrict__ partial, int kchunk) {
  __shared__ __align__(16) unsigned short As[128 * 64];
  __shared__ __align__(16) unsigned short Bs[128 * 64];

  const int tid = threadIdx.x;
  const int lane = tid & 63;
  const int wid = tid >> 6;
  const int wr = wid >> 1, wc = wid & 1;
  const int rm0 = blockIdx.y * 128;
  const int cn0 = blockIdx.x * 128;
  const int kbeg = blockIdx.z * kchunk;

  f32x4 acc[4][4];
#pragma unroll
  for (int m = 0; m < 4; ++m)
#pragma unroll
    for (int n = 0; n < 4; ++n) acc[m][n] = (f32x4){0.f, 0.f, 0.f, 0.f};

  const char* abase = (const char*)hA;
  const char* bbase = (const char*)w2t;

  for (int k0 = kbeg; k0 < kbeg + kchunk; k0 += 64) {
    __syncthreads();
#pragma unroll
    for (int j = 0; j < 4; ++j) {
      int f = j * 4096 + tid * 16;
      int row = f >> 7, inrow = f & 127;
      gload16(abase + ((size_t)(rm0 + row) * W_TOT + k0) * 2 + inrow,
              (char*)As + j * 4096 + wid * 1024);
      gload16(bbase + ((size_t)(cn0 + row) * W_TOT + k0) * 2 + inrow,
              (char*)Bs + j * 4096 + wid * 1024);
    }
    __syncthreads();
#pragma unroll
    for (int kk = 0; kk < 2; ++kk) {
      bf16x8 af[4], bfr[4];
#pragma unroll
      for (int m = 0; m < 4; ++m)
        af[m] = *(const bf16x8*)((const char*)As +
                 (wr * 64 + m * 16 + (lane & 15)) * 128 + kk * 64 + (lane >> 4) * 16);
#pragma unroll
      for (int n = 0; n < 4; ++n)
        bfr[n] = *(const bf16x8*)((const char*)Bs +
                 (wc * 64 + n * 16 + (lane & 15)) * 128 + kk * 64 + (lane >> 4) * 16);
#pragma unroll
      for (int m = 0; m < 4; ++m)
#pragma unroll
        for (int n = 0; n < 4; ++n)
          acc[m][n] = __builtin_amdgcn_mfma_f32_16x16x32_bf16(af[m], bfr[n], acc[m][n], 0, 0, 0);
    }
  }

  float* pbase = partial + (size_t)blockIdx.z * T_TOK * D_EMB;
  const int r0 = (lane >> 4) * 4;
  const int cl = lane & 15;
#pragma unroll
  for (int n = 0; n < 4; ++n) {
    int ng = cn0 + wc * 64 + n * 16 + cl;
#pragma unroll
    for (int m = 0; m < 4; ++m) {
      int rl = wr * 64 + m * 16 + r0;
#pragma unroll
      for (int r = 0; r < 4; ++r)
        pbase[(size_t)(rm0 + rl + r) * D_EMB + ng] = acc[m][n][r];
    }
  }
}

__global__ __launch_bounds__(256) void reduce_kernel(
    const float* __restrict__ partial, float* __restrict__ out, int splits) {
  int i = (blockIdx.x * 256 + threadIdx.x) * 4;
  if (i >= T_TOK * D_EMB) return;
  float4 s = *(const float4*)(partial + i);
  for (int sp = 1; sp < splits; ++sp) {
    float4 v = *(const float4*)(partial + (size_t)sp * T_TOK * D_EMB + i);
    s.x += v.x; s.y += v.y; s.z += v.z; s.w += v.w;
  }
  *(float4*)(out + i) = s;
}

// ---------------- launcher ----------------

extern "C" void kernel_launch(void* const* d_in, const int* in_sizes, int n_in,
                              void* d_out, int out_size, void* d_ws, size_t ws_size,
                              hipStream_t stream) {
  const float* x = (const float*)d_in[0];
  const float* router_w = (const float*)d_in[1];
  const float* w1 = (const float*)d_in[2];
  const float* w2 = (const float*)d_in[3];
  float* out = (float*)d_out;

  char* ws = (char*)d_ws;
  size_t off = 0;
  auto alloc = [&](size_t bytes) {
    char* p = ws + off;
    off += (bytes + 255) & ~(size_t)255;
    return p;
  };
  unsigned short* xb  = (unsigned short*)alloc((size_t)T_TOK * D_EMB * 2);
  unsigned short* w1t = (unsigned short*)alloc((size_t)W_TOT * D_EMB * 2);
  unsigned short* w2t = (unsigned short*)alloc((size_t)D_EMB * W_TOT * 2);
  unsigned short* h   = (unsigned short*)alloc((size_t)T_TOK * W_TOT * 2);
  float* comb         = (float*)alloc((size_t)T_TOK * N_EXP * 4);

  // split-K for GEMM2: pick largest divisor of 192 (=12288/64) that fits in ws
  int splits = 1;
  {
    size_t remain = (ws_size > off) ? ws_size - off : 0;
    const int cand[5] = {8, 6, 4, 3, 2};
    for (int c = 0; c < 5; ++c) {
      if ((size_t)cand[c] * T_TOK * D_EMB * 4 <= remain) { splits = cand[c]; break; }
    }
  }
  float* partial = (splits > 1) ? (float*)alloc((size_t)splits * T_TOK * D_EMB * 4) : out;
  int kchunk = W_TOT / splits;

  cvt_bf16_kernel<<<(T_TOK * D_EMB) / 1024, 256, 0, stream>>>(x, xb, T_TOK * D_EMB);
  transpose_cvt_kernel<<<dim3(W_TOT / 32, D_EMB / 32), 256, 0, stream>>>(w1, w1t, D_EMB, W_TOT);
  transpose_cvt_kernel<<<dim3(D_EMB / 32, W_TOT / 32), 256, 0, stream>>>(w2, w2t, W_TOT, D_EMB);
  router_kernel<<<T_TOK / 4, 256, 0, stream>>>(x, router_w, comb);

  gemm1_kernel<<<dim3(W_TOT / 128, T_TOK / 128), 256, 0, stream>>>(xb, w1t, comb, h);
  gemm2_kernel<<<dim3(D_EMB / 128, T_TOK / 128, splits), 256, 0, stream>>>(h, w2t, partial, kchunk);
  if (splits > 1)
    reduce_kernel<<<(T_TOK * D_EMB) / 1024, 256, 0, stream>>>(partial, out, splits);
}